// Round 10
// baseline (1220.455 us; speedup 1.0000x reference)
//
#include <hip/hip_runtime.h>

#define BB 8
#define NN 4096
#define CIN 64
#define COUTC 128
#define NPT 1024
#define KNN 24

typedef unsigned short u16;
typedef unsigned int u32;
typedef unsigned long long u64;

using short8v = __attribute__((ext_vector_type(8))) short;
using f32x4  = __attribute__((ext_vector_type(4))) float;
using f32x2  = __attribute__((ext_vector_type(2))) float;

__device__ __forceinline__ u16 f2bf(float f){ u32 u=__float_as_uint(f); u += 0x7FFFu + ((u>>16)&1u); return (u16)(u>>16); }
__device__ __forceinline__ float bf2f(u16 h){ return __uint_as_float(((u32)h)<<16); }

template<int C> __device__ __forceinline__ float dppmax_f32(float x){
  int y=__builtin_amdgcn_update_dpp(__float_as_int(x),__float_as_int(x),C,0xF,0xF,false);
  return fmaxf(x,__int_as_float(y));
}
template<int C> __device__ __forceinline__ u32 dppmin_u32(u32 x){
  u32 y=(u32)__builtin_amdgcn_update_dpp((int)x,(int)x,C,0xF,0xF,false);
  return y<x?y:x;
}
template<int C> __device__ __forceinline__ void dppmax_u64p(u32& lo, u32& hi){
  u32 nlo=(u32)__builtin_amdgcn_update_dpp((int)lo,(int)lo,C,0xF,0xF,false);
  u32 nhi=(u32)__builtin_amdgcn_update_dpp((int)hi,(int)hi,C,0xF,0xF,false);
  bool g=(nhi>hi)||((nhi==hi)&&(nlo>lo));
  lo=g?nlo:lo; hi=g?nhi:hi;
}
__device__ __forceinline__ f32x2 vmin2(f32x2 a, f32x2 b){
#if __has_builtin(__builtin_elementwise_min)
  return __builtin_elementwise_min(a,b);
#else
  f32x2 r; r.x=fminf(a.x,b.x); r.y=fminf(a.y,b.y); return r;
#endif
}
__device__ __forceinline__ f32x2 vmax2(f32x2 a, f32x2 b){
#if __has_builtin(__builtin_elementwise_max)
  return __builtin_elementwise_max(a,b);
#else
  f32x2 r; r.x=fmaxf(a.x,b.x); r.y=fmaxf(a.y,b.y); return r;
#endif
}

// ---------------- transpose x [B,64,N](f32) -> xt [B,N,64](f32) ----------------
__global__ __launch_bounds__(256) void xt_kern(const float* __restrict__ x, float* __restrict__ xt){
  __shared__ float tile[64][68];
  int blk=blockIdx.x; int b=blk>>6; int n0=(blk&63)<<6;
  int t=threadIdx.x;
  {
    int c=t>>2, nj=(t&3)*16;
    const float4* gp=reinterpret_cast<const float4*>(x + ((size_t)(b*64+c))*NN + n0+nj);
    #pragma unroll
    for(int j=0;j<4;j++){
      float4 v=gp[j];
      *reinterpret_cast<float4*>(&tile[c][nj+4*j])=v;
    }
  }
  __syncthreads();
  {
    int n=t>>2, c16=(t&3)*16;
    size_t base=((size_t)(b*NN+n0+n))*64 + c16;
    #pragma unroll
    for(int j=0;j<4;j++){
      *reinterpret_cast<float4*>(xt+base+4*j)=
        make_float4(tile[c16+4*j][n],tile[c16+4*j+1][n],tile[c16+4*j+2][n],tile[c16+4*j+3][n]);
    }
  }
}

// ---------------- sn[b][n] = sum(xyz^2) in f32, ref op order ----------------
__global__ __launch_bounds__(256) void sn_kern(const float* __restrict__ xyz, float* __restrict__ sn){
  int i=blockIdx.x*256+threadIdx.x; // exactly 32768
  const float* p=xyz+(size_t)i*3;
  float x=p[0], y=p[1], z=p[2];
  sn[i]=__fadd_rn(__fadd_rn(__fmul_rn(x,x),__fmul_rn(y,y)),__fmul_rn(z,z));
}

// ---------------- FPS: 2 batches per block as half-wave SIMD lanes ----------------
// lanes 0-31 of each wave = batch 2*blk, lanes 32-63 = batch 2*blk+1.
// One instruction stream serves both chains; one barrier/iter; merged 8-entry
// cross-wave reduce via quad-perm DPP (quad0 = A-keys, quad1 = B-keys).
__global__ __launch_bounds__(256) void fps_kern(const float* __restrict__ xyz,
    const int* __restrict__ far0, int* __restrict__ fps_idx)
{
  __shared__ float4 lp[2][NN];     // [half][point] : 128 KB
  __shared__ u64 mkey[2][8];       // [parity][entry] 0-3 = A waves, 4-7 = B waves
  const int t=threadIdx.x, w=t>>6, l=t&63;
  const int half=l>>5, lh=l&31;
  const int b=blockIdx.x*2+half;
  const int pbase=w*1024+lh*32;    // lane's first local point index (contiguous 32)
  f32x2 px2[16],py2[16],pz2[16],d2v[16];
  {
    const float4* gp=reinterpret_cast<const float4*>(xyz+((size_t)b*NN+pbase)*3);
    #pragma unroll
    for(int h2=0;h2<2;h2++){
      float4 q[12];
      #pragma unroll
      for(int i=0;i<12;i++) q[i]=gp[h2*12+i];
      const float* v=reinterpret_cast<const float*>(q);
      #pragma unroll
      for(int j=0;j<8;j++){
        int jj=h2*8+j;
        px2[jj]=(f32x2){v[6*j+0],v[6*j+3]};
        py2[jj]=(f32x2){v[6*j+1],v[6*j+4]};
        pz2[jj]=(f32x2){v[6*j+2],v[6*j+5]};
        lp[half][pbase+2*jj  ]=make_float4(v[6*j+0],v[6*j+1],v[6*j+2],0.f);
        lp[half][pbase+2*jj+1]=make_float4(v[6*j+3],v[6*j+4],v[6*j+5],0.f);
        d2v[jj]=(f32x2){1e10f,1e10f};
      }
    }
  }
  __syncthreads();
  int far=far0[b];
  float4 c=lp[half][far];
  int par=0;
  for(int it=0;it<NPT;++it){
    if(w==0&&lh==0) fps_idx[b*NPT+it]=far;   // t==0 (A) and t==32 (B)
    f32x2 cx2=(f32x2){c.x,c.x}, cy2=(f32x2){c.y,c.y}, cz2=(f32x2){c.z,c.z};
    #pragma unroll
    for(int j=0;j<16;j++){
      f32x2 dx=px2[j]-cx2, dy=py2[j]-cy2, dz=pz2[j]-cz2;
      f32x2 d=(dx*dx+dy*dy)+dz*dz;           // packed ops, exact per-element _rn order
      d2v[j]=vmin2(d2v[j],d);
    }
    f32x2 m2=d2v[0];
    #pragma unroll
    for(int j=1;j<16;j++) m2=vmax2(m2,d2v[j]);
    float m0=fmaxf(m2.x,m2.y);
    if(it==NPT-1) break;
    // 32-lane reduce per half: lanes 31 / 63 hold half-maxes after 5 DPP stages
    float r=m0;
    r=dppmax_f32<0x111>(r); r=dppmax_f32<0x112>(r); r=dppmax_f32<0x114>(r);
    r=dppmax_f32<0x118>(r); r=dppmax_f32<0x142>(r);
    float wmaxA=__int_as_float(__builtin_amdgcn_readlane(__float_as_int(r),31));
    float wmaxB=__int_as_float(__builtin_amdgcn_readlane(__float_as_int(r),63));
    float wv=half?wmaxB:wmaxA;
    u64 bal=__ballot(m0==wv);
    int winA=(int)__ffsll((unsigned long long)(bal&0xFFFFFFFFull))-1;
    int winB=32+(int)__ffsll((unsigned long long)(bal>>32))-1;
    int myj=31;
    #pragma unroll
    for(int j=15;j>=0;--j){          // first (lowest) local index wins
      if(d2v[j].y==m0) myj=2*j+1;
      if(d2v[j].x==m0) myj=2*j;
    }
    int gidx=pbase+myj;
    int widxA=__builtin_amdgcn_readlane(gidx,winA);
    int widxB=__builtin_amdgcn_readlane(gidx,winB);
    if(l==0)  mkey[par][w]  =(((u64)__float_as_uint(wmaxA))<<32)|(u32)(~(u32)((widxA<<2)|w));
    if(l==32) mkey[par][4+w]=(((u64)__float_as_uint(wmaxB))<<32)|(u32)(~(u32)((widxB<<2)|w));
    __syncthreads();
    // merged 8-entry reduce: lane reads entry (l&7); quad-perm merges quads independently
    u64 k=mkey[par][l&7];
    u32 klo=(u32)k, khi=(u32)(k>>32);
    dppmax_u64p<0xB1>(klo,khi);   // quad_perm [1,0,3,2]
    dppmax_u64p<0x4E>(klo,khi);   // quad_perm [2,3,0,1]
    u32 loA=(u32)__builtin_amdgcn_readlane((int)klo,0);
    u32 loB=(u32)__builtin_amdgcn_readlane((int)klo,4);
    int farA=(int)((~loA)>>2)&4095;
    int farB=(int)((~loB)>>2)&4095;
    far=half?farB:farA;
    c=lp[half][far];
    par^=1;
  }
}

// ---------------- kNN: 24-round DPP tournament, cached local min, 1 barrier/round ----------------
__global__ __launch_bounds__(256) void knn_kern(const float* __restrict__ xyz,
  const float* __restrict__ sn, const int* __restrict__ fps,
  const float* __restrict__ xt, u16* __restrict__ edge, float* __restrict__ outxyz)
{
  __shared__ u64 mkey[2][4];
  __shared__ int sel[KNN];
  const int m=blockIdx.x, b=m>>10;
  const int t=threadIdx.x, w=t>>6, l=t&63;
  const int ctr=fps[m];
  const float sp=sn[b*NN+ctr];
  float cx,cy,cz;
  { const float* cp=xyz+((size_t)b*NN+ctr)*3; cx=cp[0]; cy=cp[1]; cz=cp[2]; }
  u32 key[16];
  {
    float4 q[12];
    const float4* gp=reinterpret_cast<const float4*>(xyz+((size_t)b*NN)*3+(size_t)t*48);
    #pragma unroll
    for(int i=0;i<12;i++) q[i]=gp[i];
    const float* v=reinterpret_cast<const float*>(q);
    float snl[16];
    const float4* sp4=reinterpret_cast<const float4*>(sn+b*NN+t*16);
    #pragma unroll
    for(int i=0;i<4;i++){ float4 s4=sp4[i]; snl[4*i]=s4.x; snl[4*i+1]=s4.y; snl[4*i+2]=s4.z; snl[4*i+3]=s4.w; }
    #pragma unroll
    for(int j=0;j<16;j++){
      float nx=v[3*j], ny=v[3*j+1], nz=v[3*j+2];
      float dot=__fadd_rn(__fadd_rn(__fmul_rn(cx,nx),__fmul_rn(cy,ny)),__fmul_rn(cz,nz));
      float d2=__fsub_rn(__fadd_rn(sp,snl[j]),__fmul_rn(2.f,dot));
      u32 bbv=__float_as_uint(d2);
      key[j]=(bbv&0x80000000u)?~bbv:(bbv|0x80000000u); // monotone u32 key
    }
  }
  // cached per-thread (min,argmin); rescan only when this thread wins
  u32 loc=0xFFFFFFFFu; int myj=0;
  #pragma unroll
  for(int j=15;j>=0;--j){ if(key[j]<=loc){ loc=key[j]; myj=j; } }
  int par=0;
  for(int rd=0;rd<KNN;rd++){
    u32 r=loc;
    r=dppmin_u32<0x111>(r); r=dppmin_u32<0x112>(r); r=dppmin_u32<0x114>(r);
    r=dppmin_u32<0x118>(r); r=dppmin_u32<0x142>(r); r=dppmin_u32<0x143>(r);
    u32 wmin=(u32)__builtin_amdgcn_readlane((int)r,63);
    u64 bal=__ballot(loc==wmin);
    int winlane=__ffsll((unsigned long long)bal)-1;
    int widx_w=__builtin_amdgcn_readlane(t*16+myj,winlane);
    if(l==0) mkey[par][w]=(((u64)wmin)<<32)|(u32)widx_w;  // min key, tie -> min idx
    __syncthreads();
    u64 b0=mkey[par][0],b1=mkey[par][1],b2=mkey[par][2],b3=mkey[par][3];
    u64 bb0=b0<b1?b0:b1, bb1=b2<b3?b2:b3, best=bb0<bb1?bb0:bb1;
    int widx=(int)(u32)(best&0xFFFFFFFFull);
    if(t==(widx>>4)){
      key[widx&15]=0xFFFFFFFFu;
      loc=0xFFFFFFFFu; myj=0;
      #pragma unroll
      for(int j=15;j>=0;--j){ if(key[j]<=loc){ loc=key[j]; myj=j; } }
    }
    if(t==0) sel[rd]=widx;
    par^=1;
  }
  if(t<3) outxyz[(size_t)m*3+t]=xyz[((size_t)b*NN+ctr)*3+t];
  __syncthreads();
  {
    int r=t>>3, c0=(t&7)*8;
    if(r<KNN){
      int nb=sel[r];
      const float* np_=xt+((size_t)b*NN+nb)*64+c0;
      const float* cp_=xt+((size_t)b*NN+ctr)*64+c0;
      float4 n0=*reinterpret_cast<const float4*>(np_);
      float4 n1=*reinterpret_cast<const float4*>(np_+4);
      float4 c0v=*reinterpret_cast<const float4*>(cp_);
      float4 c1v=*reinterpret_cast<const float4*>(cp_+4);
      u32 ov[4];
      ov[0]=(u32)f2bf(__fsub_rn(n0.x,c0v.x))|((u32)f2bf(__fsub_rn(n0.y,c0v.y))<<16);
      ov[1]=(u32)f2bf(__fsub_rn(n0.z,c0v.z))|((u32)f2bf(__fsub_rn(n0.w,c0v.w))<<16);
      ov[2]=(u32)f2bf(__fsub_rn(n1.x,c1v.x))|((u32)f2bf(__fsub_rn(n1.y,c1v.y))<<16);
      ov[3]=(u32)f2bf(__fsub_rn(n1.z,c1v.z))|((u32)f2bf(__fsub_rn(n1.w,c1v.w))<<16);
      *reinterpret_cast<uint4*>(edge+((size_t)m*KNN+r)*64+c0)=make_uint4(ov[0],ov[1],ov[2],ov[3]);
    }
  }
}

// ---------------- GEMM: Z[R x 128] = act(A)[R x KD] @ W[128 x KD]^T + stats partials ----------------
template<int KD, bool XF>
__global__ __launch_bounds__(256) void gemm_bn(
    const u16* __restrict__ A, const float* __restrict__ W,
    const float* __restrict__ af, const float* __restrict__ cf,
    u16* __restrict__ Z, float* __restrict__ pSum, float* __restrict__ pSq,
    int nblk4)
{
  extern __shared__ char smem[];
  u16* lA=(u16*)smem;
  u16* lW=lA+128*KD;
  const int t=threadIdx.x, blk=blockIdx.x;
  constexpr int TPR=KD/8;
  constexpr int RPP=256/TPR;
  constexpr int NPASS=128/RPP;
  const int rl=t/TPR, c0=(t%TPR)*8;
  float ax[8], cxx[8];
  if constexpr (XF){
    #pragma unroll
    for(int j=0;j<8;j++){ ax[j]=af[c0+j]; cxx[j]=cf[c0+j]; }
  }
  #pragma unroll
  for(int p=0;p<NPASS;p++){
    int row=p*RPP+rl;
    uint4 v=*reinterpret_cast<const uint4*>(A+((size_t)blk*128+row)*KD+c0);
    if constexpr (XF){
      u32 in[4]={v.x,v.y,v.z,v.w}; u32 out[4];
      #pragma unroll
      for(int q2=0;q2<4;q2++){
        float f0=__uint_as_float((in[q2]&0xFFFFu)<<16);
        float f1=__uint_as_float(in[q2]&0xFFFF0000u);
        f0=fmaxf(fmaf(ax[2*q2],f0,cxx[2*q2]),0.f);
        f1=fmaxf(fmaf(ax[2*q2+1],f1,cxx[2*q2+1]),0.f);
        out[q2]=(u32)f2bf(f0)|((u32)f2bf(f1)<<16);
      }
      v.x=out[0]; v.y=out[1]; v.z=out[2]; v.w=out[3];
    }
    int byte=row*(KD*2)+c0*2; byte^=(row&7)<<4;
    *reinterpret_cast<uint4*>((char*)lA+byte)=v;
    // W: f32 -> bf16 pack
    const float* wp_=W+(size_t)row*KD+c0;
    float4 w0=*reinterpret_cast<const float4*>(wp_);
    float4 w1=*reinterpret_cast<const float4*>(wp_+4);
    uint4 wv;
    wv.x=(u32)f2bf(w0.x)|((u32)f2bf(w0.y)<<16);
    wv.y=(u32)f2bf(w0.z)|((u32)f2bf(w0.w)<<16);
    wv.z=(u32)f2bf(w1.x)|((u32)f2bf(w1.y)<<16);
    wv.w=(u32)f2bf(w1.z)|((u32)f2bf(w1.w)<<16);
    int wbyte=row*(KD*2)+c0*2; wbyte^=(row&7)<<4;
    *reinterpret_cast<uint4*>((char*)lW+wbyte)=wv;
  }
  __syncthreads();
  const int l=t&63, w2=t>>6;
  const int l15=l&15, qq=l>>4;
  f32x4 acc[2][8];
  #pragma unroll
  for(int r=0;r<2;r++)
    #pragma unroll
    for(int f=0;f<8;f++) acc[r][f]=(f32x4){0.f,0.f,0.f,0.f};
  #pragma unroll
  for(int s=0;s<KD/32;s++){
    short8v a[2];
    #pragma unroll
    for(int r=0;r<2;r++){
      int row=w2*32+r*16+l15;
      int byte=row*(KD*2)+s*64+qq*16; byte^=(row&7)<<4;
      a[r]=*reinterpret_cast<const short8v*>((char*)lA+byte);
    }
    #pragma unroll
    for(int f=0;f<8;f++){
      int row=f*16+l15;
      int byte=row*(KD*2)+s*64+qq*16; byte^=(row&7)<<4;
      short8v bb=*reinterpret_cast<const short8v*>((char*)lW+byte);
      acc[0][f]=__builtin_amdgcn_mfma_f32_16x16x32_bf16(a[0],bb,acc[0][f],0,0,0);
      acc[1][f]=__builtin_amdgcn_mfma_f32_16x16x32_bf16(a[1],bb,acc[1][f],0,0,0);
    }
  }
  #pragma unroll
  for(int f=0;f<8;f++){
    float sv=0.f,qv=0.f;
    #pragma unroll
    for(int r=0;r<2;r++){
      int grow=blk*128+w2*32+r*16+qq*4;
      #pragma unroll
      for(int j=0;j<4;j++){
        float v=acc[r][f][j];
        Z[((size_t)(grow+j))*128+f*16+l15]=f2bf(v);
        sv+=v; qv+=v*v;
      }
    }
    sv+=__shfl_xor(sv,16); sv+=__shfl_xor(sv,32);
    qv+=__shfl_xor(qv,16); qv+=__shfl_xor(qv,32);
    if(l<16){
      int col=f*16+l15;
      pSum[(size_t)col*nblk4+blk*4+w2]=sv;
      pSq [(size_t)col*nblk4+blk*4+w2]=qv;
    }
  }
}

// ---------------- stats reduce: one block per channel -> a, c ----------------
__global__ __launch_bounds__(256) void stats_kern(
  const float* __restrict__ pSum, const float* __restrict__ pSq,
  const float* __restrict__ g, const float* __restrict__ bb,
  float* __restrict__ af, float* __restrict__ cf, int nparts, float inv_cnt)
{
  int ch=blockIdx.x, t=threadIdx.x;
  float s=0.f,q=0.f;
  for(int i=t;i<nparts;i+=256){ s+=pSum[(size_t)ch*nparts+i]; q+=pSq[(size_t)ch*nparts+i]; }
  #pragma unroll
  for(int o=1;o<64;o<<=1){ s+=__shfl_xor(s,o); q+=__shfl_xor(q,o); }
  __shared__ float ls[4], lq[4];
  int w=t>>6, l=t&63;
  if(l==0){ ls[w]=s; lq[w]=q; }
  __syncthreads();
  if(t==0){
    float S=ls[0]+ls[1]+ls[2]+ls[3], Q=lq[0]+lq[1]+lq[2]+lq[3];
    float mu=S*inv_cnt, var=Q*inv_cnt-mu*mu;
    float a=g[ch]/sqrtf(var+1e-5f);
    af[ch]=a; cf[ch]=bb[ch]-mu*a;
  }
}

// ---------------- pool: h = max_k relu(bn3(z3) + relu(bn1(z1))) ----------------
__global__ __launch_bounds__(256) void pool_kern(const u16* __restrict__ z3, const u16* __restrict__ z1,
  const float* __restrict__ af1, const float* __restrict__ cf1,
  const float* __restrict__ af3, const float* __restrict__ cf3, u16* __restrict__ pooled)
{
  int t=threadIdx.x;
  int g=blockIdx.x*2+(t>>7);
  int c=t&127;
  float a1=af1[c],c1=cf1[c],a3=af3[c],c3=cf3[c];
  float mmax=0.f;
  size_t base=(size_t)g*KNN*128+c;
  #pragma unroll 4
  for(int k=0;k<KNN;k++){
    float v3=bf2f(z3[base+(size_t)k*128]);
    float v1=bf2f(z1[base+(size_t)k*128]);
    float z1p=fmaxf(fmaf(a1,v1,c1),0.f);
    float v=fmaf(a3,v3,c3)+z1p;
    mmax=fmaxf(mmax,fmaxf(v,0.f));
  }
  pooled[(size_t)g*128+c]=f2bf(mmax);
}

// ---------------- final: out[b,o,p] = relu(bn5(z5) + pooled) (f32), transposed write ----------------
__global__ __launch_bounds__(256) void final_kern(const u16* __restrict__ z5,
  const u16* __restrict__ pooled, const float* __restrict__ af, const float* __restrict__ cf,
  float* __restrict__ outh)
{
  __shared__ float tile[64][68];
  int blk=blockIdx.x; int b=blk>>5; int tl=blk&31; int p0=(tl&15)<<6; int o0=(tl>>4)<<6;
  int t=threadIdx.x;
  {
    int pl=t>>2, o1=(t&3)*16;
    size_t base=((size_t)(b*1024+p0+pl))*128 + o0+o1;
    #pragma unroll
    for(int h2=0;h2<2;h2++){
      uint4 v5=*reinterpret_cast<const uint4*>(z5+base+h2*8);
      uint4 vp=*reinterpret_cast<const uint4*>(pooled+base+h2*8);
      u32 a5[4]={v5.x,v5.y,v5.z,v5.w}; u32 pp[4]={vp.x,vp.y,vp.z,vp.w};
      #pragma unroll
      for(int q2=0;q2<4;q2++){
        int oj=o1+h2*8+q2*2;
        float g0=af[o0+oj],h0=cf[o0+oj],g1=af[o0+oj+1],h1=cf[o0+oj+1];
        float f0=__uint_as_float((a5[q2]&0xFFFFu)<<16);
        float f1=__uint_as_float(a5[q2]&0xFFFF0000u);
        float q0=__uint_as_float((pp[q2]&0xFFFFu)<<16);
        float q1=__uint_as_float(pp[q2]&0xFFFF0000u);
        tile[oj][pl]  =fmaxf(fmaf(g0,f0,h0)+q0,0.f);
        tile[oj+1][pl]=fmaxf(fmaf(g1,f1,h1)+q1,0.f);
      }
    }
  }
  __syncthreads();
  {
    int ol=t>>2, pj=(t&3)*16;
    size_t obase=((size_t)(b*128+o0+ol))*1024 + p0+pj;
    #pragma unroll
    for(int j=0;j<4;j++){
      *reinterpret_cast<float4*>(outh+obase+4*j)=
        make_float4(tile[ol][pj+4*j],tile[ol][pj+4*j+1],tile[ol][pj+4*j+2],tile[ol][pj+4*j+3]);
    }
  }
}

// ---------------- launch ----------------
extern "C" void kernel_launch(void* const* d_in, const int* in_sizes, int n_in,
                              void* d_out, int out_size, void* d_ws, size_t ws_size,
                              hipStream_t stream)
{
  (void)in_sizes; (void)n_in; (void)out_size; (void)ws_size;
  const float* xyz   =(const float*)d_in[0];
  const float* x     =(const float*)d_in[1];
  const int*   far0  =(const int*)d_in[2];
  const float* W_proj=(const float*)d_in[3];
  const float* g_proj=(const float*)d_in[4];
  const float* b_proj=(const float*)d_in[5];
  const float* W_la1 =(const float*)d_in[6];
  const float* g_la1 =(const float*)d_in[7];
  const float* b_la1 =(const float*)d_in[8];
  const float* W_la2 =(const float*)d_in[9];
  const float* g_la2 =(const float*)d_in[10];
  const float* b_la2 =(const float*)d_in[11];
  const float* W_ca1 =(const float*)d_in[12];
  const float* g_ca1 =(const float*)d_in[13];
  const float* b_ca1 =(const float*)d_in[14];
  const float* W_ca2 =(const float*)d_in[15];
  const float* g_ca2 =(const float*)d_in[16];
  const float* b_ca2 =(const float*)d_in[17];

  char* ws=(char*)d_ws;
  const size_t OFF_XT =0;          // xt f32: 8,388,608
  const size_t OFF_SN =8388608;    // 131,072
  const size_t OFF_FPS=8519680;    // 32,768
  const size_t OFF_AF =8552448;    // 2,560
  const size_t OFF_CF =8555008;    // 2,560
  const size_t OFF_PS =8557568;    // 3,145,728
  const size_t OFF_PQ =11703296;   // 3,145,728
  const size_t OFF_PL =14849024;   // 2,097,152
  const size_t OFF_Z4 =16946176;   // 2,097,152
  const size_t OFF_Z5 =19043328;   // 2,097,152
  const size_t OFF_Z1 =21140480;   // 50,331,648
  const size_t OFF_B2 =71472128;   // 50,331,648: edge (first 25MB) -> z2 -> z3 in-place

  float* xt  =(float*)(ws+OFF_XT);
  float* sn  =(float*)(ws+OFF_SN);
  int* fps   =(int*)(ws+OFF_FPS);
  float* af  =(float*)(ws+OFF_AF);
  float* cf  =(float*)(ws+OFF_CF);
  float* pS  =(float*)(ws+OFF_PS);
  float* pQ  =(float*)(ws+OFF_PQ);
  u16* pooled=(u16*)(ws+OFF_PL);
  u16* z4    =(u16*)(ws+OFF_Z4);
  u16* z5    =(u16*)(ws+OFF_Z5);
  u16* z1    =(u16*)(ws+OFF_Z1);
  u16* edge  =(u16*)(ws+OFF_B2);
  u16* z2    =(u16*)(ws+OFF_B2);
  u16* z3    =(u16*)(ws+OFF_B2);  // in-place over z2 (block-local safe)
  float* outxyz=(float*)d_out;
  float* outh  =(float*)d_out+24576;

  const float invL=1.f/196608.f, invC=1.f/8192.f;

  xt_kern<<<512,256,0,stream>>>(x,xt);
  sn_kern<<<128,256,0,stream>>>(xyz,sn);
  fps_kern<<<4,256,0,stream>>>(xyz,far0,fps);
  knn_kern<<<8192,256,0,stream>>>(xyz,sn,fps,xt,edge,outxyz);

  gemm_bn<64,false><<<1536,256,32768,stream>>>(edge,W_proj,nullptr,nullptr,z1,pS,pQ,6144);
  stats_kern<<<128,256,0,stream>>>(pS,pQ,g_proj,b_proj,af+0,cf+0,6144,invL);

  gemm_bn<128,true><<<1536,256,65536,stream>>>(z1,W_la1,af+0,cf+0,z2,pS,pQ,6144);
  stats_kern<<<128,256,0,stream>>>(pS,pQ,g_la1,b_la1,af+128,cf+128,6144,invL);

  gemm_bn<128,true><<<1536,256,65536,stream>>>(z2,W_la2,af+128,cf+128,z3,pS,pQ,6144);
  stats_kern<<<128,256,0,stream>>>(pS,pQ,g_la2,b_la2,af+256,cf+256,6144,invL);

  pool_kern<<<4096,256,0,stream>>>(z3,z1,af+0,cf+0,af+256,cf+256,pooled);

  gemm_bn<128,false><<<64,256,65536,stream>>>(pooled,W_ca1,nullptr,nullptr,z4,pS,pQ,256);
  stats_kern<<<128,256,0,stream>>>(pS,pQ,g_ca1,b_ca1,af+384,cf+384,256,invC);

  gemm_bn<128,true><<<64,256,65536,stream>>>(z4,W_ca2,af+384,cf+384,z5,pS,pQ,256);
  stats_kern<<<128,256,0,stream>>>(pS,pQ,g_ca2,b_ca2,af+512,cf+512,256,invC);

  final_kern<<<256,256,0,stream>>>(z5,pooled,af+512,cf+512,outh);
}

// Round 11
// 806.986 us; speedup vs baseline: 1.5124x; 1.5124x over previous
//
#include <hip/hip_runtime.h>

#define BB 8
#define NN 4096
#define CIN 64
#define COUTC 128
#define NPT 1024
#define KNN 24

typedef unsigned short u16;
typedef unsigned int u32;
typedef unsigned long long u64;

using short8v = __attribute__((ext_vector_type(8))) short;
using f32x4  = __attribute__((ext_vector_type(4))) float;
using f32x2  = __attribute__((ext_vector_type(2))) float;

__device__ __forceinline__ u16 f2bf(float f){ u32 u=__float_as_uint(f); u += 0x7FFFu + ((u>>16)&1u); return (u16)(u>>16); }
__device__ __forceinline__ float bf2f(u16 h){ return __uint_as_float(((u32)h)<<16); }

template<int C> __device__ __forceinline__ float dppmax_f32(float x){
  int y=__builtin_amdgcn_update_dpp(__float_as_int(x),__float_as_int(x),C,0xF,0xF,false);
  return fmaxf(x,__int_as_float(y));
}
template<int C> __device__ __forceinline__ u32 dppmin_u32(u32 x){
  u32 y=(u32)__builtin_amdgcn_update_dpp((int)x,(int)x,C,0xF,0xF,false);
  return y<x?y:x;
}
template<int C> __device__ __forceinline__ void dppmax_u64p(u32& lo, u32& hi){
  u32 nlo=(u32)__builtin_amdgcn_update_dpp((int)lo,(int)lo,C,0xF,0xF,false);
  u32 nhi=(u32)__builtin_amdgcn_update_dpp((int)hi,(int)hi,C,0xF,0xF,false);
  bool g=(nhi>hi)||((nhi==hi)&&(nlo>lo));
  lo=g?nlo:lo; hi=g?nhi:hi;
}
__device__ __forceinline__ f32x2 vmin2(f32x2 a, f32x2 b){
#if __has_builtin(__builtin_elementwise_min)
  return __builtin_elementwise_min(a,b);
#else
  f32x2 r; r.x=fminf(a.x,b.x); r.y=fminf(a.y,b.y); return r;
#endif
}
__device__ __forceinline__ f32x2 vmax2(f32x2 a, f32x2 b){
#if __has_builtin(__builtin_elementwise_max)
  return __builtin_elementwise_max(a,b);
#else
  f32x2 r; r.x=fmaxf(a.x,b.x); r.y=fmaxf(a.y,b.y); return r;
#endif
}

// ---------------- transpose x [B,64,N](f32) -> xt [B,N,64](f32) ----------------
__global__ __launch_bounds__(256) void xt_kern(const float* __restrict__ x, float* __restrict__ xt){
  __shared__ float tile[64][68];
  int blk=blockIdx.x; int b=blk>>6; int n0=(blk&63)<<6;
  int t=threadIdx.x;
  {
    int c=t>>2, nj=(t&3)*16;
    const float4* gp=reinterpret_cast<const float4*>(x + ((size_t)(b*64+c))*NN + n0+nj);
    #pragma unroll
    for(int j=0;j<4;j++){
      float4 v=gp[j];
      *reinterpret_cast<float4*>(&tile[c][nj+4*j])=v;
    }
  }
  __syncthreads();
  {
    int n=t>>2, c16=(t&3)*16;
    size_t base=((size_t)(b*NN+n0+n))*64 + c16;
    #pragma unroll
    for(int j=0;j<4;j++){
      *reinterpret_cast<float4*>(xt+base+4*j)=
        make_float4(tile[c16+4*j][n],tile[c16+4*j+1][n],tile[c16+4*j+2][n],tile[c16+4*j+3][n]);
    }
  }
}

// ---------------- sn[b][n] = sum(xyz^2) in f32, ref op order ----------------
__global__ __launch_bounds__(256) void sn_kern(const float* __restrict__ xyz, float* __restrict__ sn){
  int i=blockIdx.x*256+threadIdx.x; // exactly 32768
  const float* p=xyz+(size_t)i*3;
  float x=p[0], y=p[1], z=p[2];
  sn[i]=__fadd_rn(__fadd_rn(__fmul_rn(x,x),__fmul_rn(y,y)),__fmul_rn(z,z));
}

// ---------------- FPS: 256 thr, packed-f32 dist, DPP argmax, raw barrier (no vmcnt drain) ----------------
__global__ __launch_bounds__(256) void fps_kern(const float* __restrict__ xyz,
    const int* __restrict__ far0, int* __restrict__ fps_idx)
{
  __shared__ float4 lp[NN];      // 64 KB
  __shared__ u64 mkey[2][4];
  const int b=blockIdx.x, t=threadIdx.x, w=t>>6, l=t&63;
  // 16 points/thread as 8 float2 lanes: px2[j] = {x(2j), x(2j+1)}
  f32x2 px2[8],py2[8],pz2[8],d2v[8];
  {
    float4 q[12];
    const float4* gp=reinterpret_cast<const float4*>(xyz+(size_t)b*NN*3)+(size_t)t*12;
    #pragma unroll
    for(int i=0;i<12;i++) q[i]=gp[i];
    const float* v=reinterpret_cast<const float*>(q);
    #pragma unroll
    for(int j=0;j<8;j++){
      px2[j]=(f32x2){v[6*j+0],v[6*j+3]};
      py2[j]=(f32x2){v[6*j+1],v[6*j+4]};
      pz2[j]=(f32x2){v[6*j+2],v[6*j+5]};
      lp[t*16+2*j  ]=make_float4(v[6*j+0],v[6*j+1],v[6*j+2],0.f);
      lp[t*16+2*j+1]=make_float4(v[6*j+3],v[6*j+4],v[6*j+5],0.f);
      d2v[j]=(f32x2){1e10f,1e10f};
    }
  }
  __syncthreads();
  int far=far0[b];
  float4 c=lp[far];
  int par=0;
  for(int it=0;it<NPT;++it){
    if(t==0) fps_idx[b*NPT+it]=far;   // fire-and-forget; never drained by the raw barrier
    f32x2 cx2=(f32x2){c.x,c.x}, cy2=(f32x2){c.y,c.y}, cz2=(f32x2){c.z,c.z};
    f32x2 m2=(f32x2){-1.f,-1.f};
    #pragma unroll
    for(int j=0;j<8;j++){
      f32x2 dx=px2[j]-cx2, dy=py2[j]-cy2, dz=pz2[j]-cz2;
      f32x2 d=(dx*dx+dy*dy)+dz*dz;     // packed ops: per-element exact _rn order
      f32x2 nd=vmin2(d2v[j],d); d2v[j]=nd;
      m2=vmax2(m2,nd);
    }
    float m0=fmaxf(m2.x,m2.y);
    if(it==NPT-1) break;
    // wave64 f32 max -> lane 63
    float r=m0;
    r=dppmax_f32<0x111>(r); r=dppmax_f32<0x112>(r); r=dppmax_f32<0x114>(r);
    r=dppmax_f32<0x118>(r); r=dppmax_f32<0x142>(r); r=dppmax_f32<0x143>(r);
    float wmax=__int_as_float(__builtin_amdgcn_readlane(__float_as_int(r),63));
    u64 bal=__ballot(m0==wmax);
    int winlane=__ffsll((unsigned long long)bal)-1;  // lowest lane = lowest global idx
    int myj=15;
    #pragma unroll
    for(int j=7;j>=0;--j){              // first (lowest) original index wins
      if(d2v[j].y==m0) myj=2*j+1;
      if(d2v[j].x==m0) myj=2*j;
    }
    int widx_w=__builtin_amdgcn_readlane(t*16+myj,winlane);
    if(l==0) mkey[par][w]=(((u64)__float_as_uint(wmax))<<32)|(u32)(~(u32)widx_w);
    // raw barrier: order LDS only (lgkmcnt), do NOT drain vmcnt -> global store stays in flight
    asm volatile("s_waitcnt lgkmcnt(0)\n\ts_barrier" ::: "memory");
    // lane-parallel merge: lane reads entry (l&3), 2 quad-perm DPP u64-max stages
    u64 k4=mkey[par][l&3];
    u32 klo=(u32)k4, khi=(u32)(k4>>32);
    dppmax_u64p<0xB1>(klo,khi);   // quad_perm [1,0,3,2]
    dppmax_u64p<0x4E>(klo,khi);   // quad_perm [2,3,0,1]
    int widx=(int)(~klo);
    far=widx;
    c=lp[widx];
    par^=1;
  }
}

// ---------------- kNN: 24-round DPP tournament, cached local min, 1 barrier/round ----------------
__global__ __launch_bounds__(256) void knn_kern(const float* __restrict__ xyz,
  const float* __restrict__ sn, const int* __restrict__ fps,
  const float* __restrict__ xt, u16* __restrict__ edge, float* __restrict__ outxyz)
{
  __shared__ u64 mkey[2][4];
  __shared__ int sel[KNN];
  const int m=blockIdx.x, b=m>>10;
  const int t=threadIdx.x, w=t>>6, l=t&63;
  const int ctr=fps[m];
  const float sp=sn[b*NN+ctr];
  float cx,cy,cz;
  { const float* cp=xyz+((size_t)b*NN+ctr)*3; cx=cp[0]; cy=cp[1]; cz=cp[2]; }
  u32 key[16];
  {
    float4 q[12];
    const float4* gp=reinterpret_cast<const float4*>(xyz+((size_t)b*NN)*3+(size_t)t*48);
    #pragma unroll
    for(int i=0;i<12;i++) q[i]=gp[i];
    const float* v=reinterpret_cast<const float*>(q);
    float snl[16];
    const float4* sp4=reinterpret_cast<const float4*>(sn+b*NN+t*16);
    #pragma unroll
    for(int i=0;i<4;i++){ float4 s4=sp4[i]; snl[4*i]=s4.x; snl[4*i+1]=s4.y; snl[4*i+2]=s4.z; snl[4*i+3]=s4.w; }
    #pragma unroll
    for(int j=0;j<16;j++){
      float nx=v[3*j], ny=v[3*j+1], nz=v[3*j+2];
      float dot=__fadd_rn(__fadd_rn(__fmul_rn(cx,nx),__fmul_rn(cy,ny)),__fmul_rn(cz,nz));
      float d2=__fsub_rn(__fadd_rn(sp,snl[j]),__fmul_rn(2.f,dot));
      u32 bbv=__float_as_uint(d2);
      key[j]=(bbv&0x80000000u)?~bbv:(bbv|0x80000000u); // monotone u32 key
    }
  }
  // cached per-thread (min,argmin); rescan only when this thread wins
  u32 loc=0xFFFFFFFFu; int myj=0;
  #pragma unroll
  for(int j=15;j>=0;--j){ if(key[j]<=loc){ loc=key[j]; myj=j; } }
  int par=0;
  for(int rd=0;rd<KNN;rd++){
    u32 r=loc;
    r=dppmin_u32<0x111>(r); r=dppmin_u32<0x112>(r); r=dppmin_u32<0x114>(r);
    r=dppmin_u32<0x118>(r); r=dppmin_u32<0x142>(r); r=dppmin_u32<0x143>(r);
    u32 wmin=(u32)__builtin_amdgcn_readlane((int)r,63);
    u64 bal=__ballot(loc==wmin);
    int winlane=__ffsll((unsigned long long)bal)-1;
    int widx_w=__builtin_amdgcn_readlane(t*16+myj,winlane);
    if(l==0) mkey[par][w]=(((u64)wmin)<<32)|(u32)widx_w;  // min key, tie -> min idx
    asm volatile("s_waitcnt lgkmcnt(0)\n\ts_barrier" ::: "memory");
    u64 b0=mkey[par][0],b1=mkey[par][1],b2=mkey[par][2],b3=mkey[par][3];
    u64 bb0=b0<b1?b0:b1, bb1=b2<b3?b2:b3, best=bb0<bb1?bb0:bb1;
    int widx=(int)(u32)(best&0xFFFFFFFFull);
    if(t==(widx>>4)){
      key[widx&15]=0xFFFFFFFFu;
      loc=0xFFFFFFFFu; myj=0;
      #pragma unroll
      for(int j=15;j>=0;--j){ if(key[j]<=loc){ loc=key[j]; myj=j; } }
    }
    if(t==0) sel[rd]=widx;
    par^=1;
  }
  if(t<3) outxyz[(size_t)m*3+t]=xyz[((size_t)b*NN+ctr)*3+t];
  __syncthreads();
  {
    int r=t>>3, c0=(t&7)*8;
    if(r<KNN){
      int nb=sel[r];
      const float* np_=xt+((size_t)b*NN+nb)*64+c0;
      const float* cp_=xt+((size_t)b*NN+ctr)*64+c0;
      float4 n0=*reinterpret_cast<const float4*>(np_);
      float4 n1=*reinterpret_cast<const float4*>(np_+4);
      float4 c0v=*reinterpret_cast<const float4*>(cp_);
      float4 c1v=*reinterpret_cast<const float4*>(cp_+4);
      u32 ov[4];
      ov[0]=(u32)f2bf(__fsub_rn(n0.x,c0v.x))|((u32)f2bf(__fsub_rn(n0.y,c0v.y))<<16);
      ov[1]=(u32)f2bf(__fsub_rn(n0.z,c0v.z))|((u32)f2bf(__fsub_rn(n0.w,c0v.w))<<16);
      ov[2]=(u32)f2bf(__fsub_rn(n1.x,c1v.x))|((u32)f2bf(__fsub_rn(n1.y,c1v.y))<<16);
      ov[3]=(u32)f2bf(__fsub_rn(n1.z,c1v.z))|((u32)f2bf(__fsub_rn(n1.w,c1v.w))<<16);
      *reinterpret_cast<uint4*>(edge+((size_t)m*KNN+r)*64+c0)=make_uint4(ov[0],ov[1],ov[2],ov[3]);
    }
  }
}

// ---------------- GEMM: Z[R x 128] = act(A)[R x KD] @ W[128 x KD]^T + stats partials ----------------
template<int KD, bool XF>
__global__ __launch_bounds__(256) void gemm_bn(
    const u16* __restrict__ A, const float* __restrict__ W,
    const float* __restrict__ af, const float* __restrict__ cf,
    u16* __restrict__ Z, float* __restrict__ pSum, float* __restrict__ pSq,
    int nblk4)
{
  extern __shared__ char smem[];
  u16* lA=(u16*)smem;
  u16* lW=lA+128*KD;
  const int t=threadIdx.x, blk=blockIdx.x;
  constexpr int TPR=KD/8;
  constexpr int RPP=256/TPR;
  constexpr int NPASS=128/RPP;
  const int rl=t/TPR, c0=(t%TPR)*8;
  float ax[8], cxx[8];
  if constexpr (XF){
    #pragma unroll
    for(int j=0;j<8;j++){ ax[j]=af[c0+j]; cxx[j]=cf[c0+j]; }
  }
  #pragma unroll
  for(int p=0;p<NPASS;p++){
    int row=p*RPP+rl;
    uint4 v=*reinterpret_cast<const uint4*>(A+((size_t)blk*128+row)*KD+c0);
    if constexpr (XF){
      u32 in[4]={v.x,v.y,v.z,v.w}; u32 out[4];
      #pragma unroll
      for(int q2=0;q2<4;q2++){
        float f0=__uint_as_float((in[q2]&0xFFFFu)<<16);
        float f1=__uint_as_float(in[q2]&0xFFFF0000u);
        f0=fmaxf(fmaf(ax[2*q2],f0,cxx[2*q2]),0.f);
        f1=fmaxf(fmaf(ax[2*q2+1],f1,cxx[2*q2+1]),0.f);
        out[q2]=(u32)f2bf(f0)|((u32)f2bf(f1)<<16);
      }
      v.x=out[0]; v.y=out[1]; v.z=out[2]; v.w=out[3];
    }
    int byte=row*(KD*2)+c0*2; byte^=(row&7)<<4;
    *reinterpret_cast<uint4*>((char*)lA+byte)=v;
    // W: f32 -> bf16 pack
    const float* wp_=W+(size_t)row*KD+c0;
    float4 w0=*reinterpret_cast<const float4*>(wp_);
    float4 w1=*reinterpret_cast<const float4*>(wp_+4);
    uint4 wv;
    wv.x=(u32)f2bf(w0.x)|((u32)f2bf(w0.y)<<16);
    wv.y=(u32)f2bf(w0.z)|((u32)f2bf(w0.w)<<16);
    wv.z=(u32)f2bf(w1.x)|((u32)f2bf(w1.y)<<16);
    wv.w=(u32)f2bf(w1.z)|((u32)f2bf(w1.w)<<16);
    int wbyte=row*(KD*2)+c0*2; wbyte^=(row&7)<<4;
    *reinterpret_cast<uint4*>((char*)lW+wbyte)=wv;
  }
  __syncthreads();
  const int l=t&63, w2=t>>6;
  const int l15=l&15, qq=l>>4;
  f32x4 acc[2][8];
  #pragma unroll
  for(int r=0;r<2;r++)
    #pragma unroll
    for(int f=0;f<8;f++) acc[r][f]=(f32x4){0.f,0.f,0.f,0.f};
  #pragma unroll
  for(int s=0;s<KD/32;s++){
    short8v a[2];
    #pragma unroll
    for(int r=0;r<2;r++){
      int row=w2*32+r*16+l15;
      int byte=row*(KD*2)+s*64+qq*16; byte^=(row&7)<<4;
      a[r]=*reinterpret_cast<const short8v*>((char*)lA+byte);
    }
    #pragma unroll
    for(int f=0;f<8;f++){
      int row=f*16+l15;
      int byte=row*(KD*2)+s*64+qq*16; byte^=(row&7)<<4;
      short8v bb=*reinterpret_cast<const short8v*>((char*)lW+byte);
      acc[0][f]=__builtin_amdgcn_mfma_f32_16x16x32_bf16(a[0],bb,acc[0][f],0,0,0);
      acc[1][f]=__builtin_amdgcn_mfma_f32_16x16x32_bf16(a[1],bb,acc[1][f],0,0,0);
    }
  }
  #pragma unroll
  for(int f=0;f<8;f++){
    float sv=0.f,qv=0.f;
    #pragma unroll
    for(int r=0;r<2;r++){
      int grow=blk*128+w2*32+r*16+qq*4;
      #pragma unroll
      for(int j=0;j<4;j++){
        float v=acc[r][f][j];
        Z[((size_t)(grow+j))*128+f*16+l15]=f2bf(v);
        sv+=v; qv+=v*v;
      }
    }
    sv+=__shfl_xor(sv,16); sv+=__shfl_xor(sv,32);
    qv+=__shfl_xor(qv,16); qv+=__shfl_xor(qv,32);
    if(l<16){
      int col=f*16+l15;
      pSum[(size_t)col*nblk4+blk*4+w2]=sv;
      pSq [(size_t)col*nblk4+blk*4+w2]=qv;
    }
  }
}

// ---------------- stats reduce: one block per channel -> a, c ----------------
__global__ __launch_bounds__(256) void stats_kern(
  const float* __restrict__ pSum, const float* __restrict__ pSq,
  const float* __restrict__ g, const float* __restrict__ bb,
  float* __restrict__ af, float* __restrict__ cf, int nparts, float inv_cnt)
{
  int ch=blockIdx.x, t=threadIdx.x;
  float s=0.f,q=0.f;
  for(int i=t;i<nparts;i+=256){ s+=pSum[(size_t)ch*nparts+i]; q+=pSq[(size_t)ch*nparts+i]; }
  #pragma unroll
  for(int o=1;o<64;o<<=1){ s+=__shfl_xor(s,o); q+=__shfl_xor(q,o); }
  __shared__ float ls[4], lq[4];
  int w=t>>6, l=t&63;
  if(l==0){ ls[w]=s; lq[w]=q; }
  __syncthreads();
  if(t==0){
    float S=ls[0]+ls[1]+ls[2]+ls[3], Q=lq[0]+lq[1]+lq[2]+lq[3];
    float mu=S*inv_cnt, var=Q*inv_cnt-mu*mu;
    float a=g[ch]/sqrtf(var+1e-5f);
    af[ch]=a; cf[ch]=bb[ch]-mu*a;
  }
}

// ---------------- pool: h = max_k relu(bn3(z3) + relu(bn1(z1))) ----------------
__global__ __launch_bounds__(256) void pool_kern(const u16* __restrict__ z3, const u16* __restrict__ z1,
  const float* __restrict__ af1, const float* __restrict__ cf1,
  const float* __restrict__ af3, const float* __restrict__ cf3, u16* __restrict__ pooled)
{
  int t=threadIdx.x;
  int g=blockIdx.x*2+(t>>7);
  int c=t&127;
  float a1=af1[c],c1=cf1[c],a3=af3[c],c3=cf3[c];
  float mmax=0.f;
  size_t base=(size_t)g*KNN*128+c;
  #pragma unroll 4
  for(int k=0;k<KNN;k++){
    float v3=bf2f(z3[base+(size_t)k*128]);
    float v1=bf2f(z1[base+(size_t)k*128]);
    float z1p=fmaxf(fmaf(a1,v1,c1),0.f);
    float v=fmaf(a3,v3,c3)+z1p;
    mmax=fmaxf(mmax,fmaxf(v,0.f));
  }
  pooled[(size_t)g*128+c]=f2bf(mmax);
}

// ---------------- final: out[b,o,p] = relu(bn5(z5) + pooled) (f32), transposed write ----------------
__global__ __launch_bounds__(256) void final_kern(const u16* __restrict__ z5,
  const u16* __restrict__ pooled, const float* __restrict__ af, const float* __restrict__ cf,
  float* __restrict__ outh)
{
  __shared__ float tile[64][68];
  int blk=blockIdx.x; int b=blk>>5; int tl=blk&31; int p0=(tl&15)<<6; int o0=(tl>>4)<<6;
  int t=threadIdx.x;
  {
    int pl=t>>2, o1=(t&3)*16;
    size_t base=((size_t)(b*1024+p0+pl))*128 + o0+o1;
    #pragma unroll
    for(int h2=0;h2<2;h2++){
      uint4 v5=*reinterpret_cast<const uint4*>(z5+base+h2*8);
      uint4 vp=*reinterpret_cast<const uint4*>(pooled+base+h2*8);
      u32 a5[4]={v5.x,v5.y,v5.z,v5.w}; u32 pp[4]={vp.x,vp.y,vp.z,vp.w};
      #pragma unroll
      for(int q2=0;q2<4;q2++){
        int oj=o1+h2*8+q2*2;
        float g0=af[o0+oj],h0=cf[o0+oj],g1=af[o0+oj+1],h1=cf[o0+oj+1];
        float f0=__uint_as_float((a5[q2]&0xFFFFu)<<16);
        float f1=__uint_as_float(a5[q2]&0xFFFF0000u);
        float q0=__uint_as_float((pp[q2]&0xFFFFu)<<16);
        float q1=__uint_as_float(pp[q2]&0xFFFF0000u);
        tile[oj][pl]  =fmaxf(fmaf(g0,f0,h0)+q0,0.f);
        tile[oj+1][pl]=fmaxf(fmaf(g1,f1,h1)+q1,0.f);
      }
    }
  }
  __syncthreads();
  {
    int ol=t>>2, pj=(t&3)*16;
    size_t obase=((size_t)(b*128+o0+ol))*1024 + p0+pj;
    #pragma unroll
    for(int j=0;j<4;j++){
      *reinterpret_cast<float4*>(outh+obase+4*j)=
        make_float4(tile[ol][pj+4*j],tile[ol][pj+4*j+1],tile[ol][pj+4*j+2],tile[ol][pj+4*j+3]);
    }
  }
}

// ---------------- launch ----------------
extern "C" void kernel_launch(void* const* d_in, const int* in_sizes, int n_in,
                              void* d_out, int out_size, void* d_ws, size_t ws_size,
                              hipStream_t stream)
{
  (void)in_sizes; (void)n_in; (void)out_size; (void)ws_size;
  const float* xyz   =(const float*)d_in[0];
  const float* x     =(const float*)d_in[1];
  const int*   far0  =(const int*)d_in[2];
  const float* W_proj=(const float*)d_in[3];
  const float* g_proj=(const float*)d_in[4];
  const float* b_proj=(const float*)d_in[5];
  const float* W_la1 =(const float*)d_in[6];
  const float* g_la1 =(const float*)d_in[7];
  const float* b_la1 =(const float*)d_in[8];
  const float* W_la2 =(const float*)d_in[9];
  const float* g_la2 =(const float*)d_in[10];
  const float* b_la2 =(const float*)d_in[11];
  const float* W_ca1 =(const float*)d_in[12];
  const float* g_ca1 =(const float*)d_in[13];
  const float* b_ca1 =(const float*)d_in[14];
  const float* W_ca2 =(const float*)d_in[15];
  const float* g_ca2 =(const float*)d_in[16];
  const float* b_ca2 =(const float*)d_in[17];

  char* ws=(char*)d_ws;
  const size_t OFF_XT =0;          // xt f32: 8,388,608
  const size_t OFF_SN =8388608;    // 131,072
  const size_t OFF_FPS=8519680;    // 32,768
  const size_t OFF_AF =8552448;    // 2,560
  const size_t OFF_CF =8555008;    // 2,560
  const size_t OFF_PS =8557568;    // 3,145,728
  const size_t OFF_PQ =11703296;   // 3,145,728
  const size_t OFF_PL =14849024;   // 2,097,152
  const size_t OFF_Z4 =16946176;   // 2,097,152
  const size_t OFF_Z5 =19043328;   // 2,097,152
  const size_t OFF_Z1 =21140480;   // 50,331,648
  const size_t OFF_B2 =71472128;   // 50,331,648: edge (first 25MB) -> z2 -> z3 in-place

  float* xt  =(float*)(ws+OFF_XT);
  float* sn  =(float*)(ws+OFF_SN);
  int* fps   =(int*)(ws+OFF_FPS);
  float* af  =(float*)(ws+OFF_AF);
  float* cf  =(float*)(ws+OFF_CF);
  float* pS  =(float*)(ws+OFF_PS);
  float* pQ  =(float*)(ws+OFF_PQ);
  u16* pooled=(u16*)(ws+OFF_PL);
  u16* z4    =(u16*)(ws+OFF_Z4);
  u16* z5    =(u16*)(ws+OFF_Z5);
  u16* z1    =(u16*)(ws+OFF_Z1);
  u16* edge  =(u16*)(ws+OFF_B2);
  u16* z2    =(u16*)(ws+OFF_B2);
  u16* z3    =(u16*)(ws+OFF_B2);  // in-place over z2 (block-local safe)
  float* outxyz=(float*)d_out;
  float* outh  =(float*)d_out+24576;

  const float invL=1.f/196608.f, invC=1.f/8192.f;

  xt_kern<<<512,256,0,stream>>>(x,xt);
  sn_kern<<<128,256,0,stream>>>(xyz,sn);
  fps_kern<<<8,256,0,stream>>>(xyz,far0,fps);
  knn_kern<<<8192,256,0,stream>>>(xyz,sn,fps,xt,edge,outxyz);

  gemm_bn<64,false><<<1536,256,32768,stream>>>(edge,W_proj,nullptr,nullptr,z1,pS,pQ,6144);
  stats_kern<<<128,256,0,stream>>>(pS,pQ,g_proj,b_proj,af+0,cf+0,6144,invL);

  gemm_bn<128,true><<<1536,256,65536,stream>>>(z1,W_la1,af+0,cf+0,z2,pS,pQ,6144);
  stats_kern<<<128,256,0,stream>>>(pS,pQ,g_la1,b_la1,af+128,cf+128,6144,invL);

  gemm_bn<128,true><<<1536,256,65536,stream>>>(z2,W_la2,af+128,cf+128,z3,pS,pQ,6144);
  stats_kern<<<128,256,0,stream>>>(pS,pQ,g_la2,b_la2,af+256,cf+256,6144,invL);

  pool_kern<<<4096,256,0,stream>>>(z3,z1,af+0,cf+0,af+256,cf+256,pooled);

  gemm_bn<128,false><<<64,256,65536,stream>>>(pooled,W_ca1,nullptr,nullptr,z4,pS,pQ,256);
  stats_kern<<<128,256,0,stream>>>(pS,pQ,g_ca1,b_ca1,af+384,cf+384,256,invC);

  gemm_bn<128,true><<<64,256,65536,stream>>>(z4,W_ca2,af+384,cf+384,z5,pS,pQ,256);
  stats_kern<<<128,256,0,stream>>>(pS,pQ,g_ca2,b_ca2,af+512,cf+512,256,invC);

  final_kern<<<256,256,0,stream>>>(z5,pooled,af+512,cf+512,outh);
}